// Round 2
// baseline (4321.576 us; speedup 1.0000x reference)
//
#include <hip/hip_runtime.h>
#include <hip/hip_bf16.h>

typedef float f32x4 __attribute__((ext_vector_type(4)));
typedef short s16x8 __attribute__((ext_vector_type(8)));
typedef float floatx4 __attribute__((ext_vector_type(4)));

#define DEV static __device__ __forceinline__

DEV void gld_lds16(const void* g, void* l) {
  __builtin_amdgcn_global_load_lds(
      (const __attribute__((address_space(1))) void*)g,
      (__attribute__((address_space(3))) void*)l, 16, 0, 0);
}

DEV short f2bf(float x) {
  union { __hip_bfloat16 h; short s; } u;
  u.h = __float2bfloat16(x);
  return u.s;
}

DEV float bf2f(short s) {
  union { unsigned u; float f; } v;
  v.u = ((unsigned)(unsigned short)s) << 16;
  return v.f;
}

DEV void split2(float x, short& hi, short& lo) {
  hi = f2bf(x);
  lo = f2bf(x - bf2f(hi));
}

DEV float sigf(float x) {
  return 1.0f / (1.0f + exp2f(x * -1.44269504f));
}

DEV float tanhf2(float x) {
  float e = exp2f(fmaxf(x, -18.0f) * -2.88539008f);
  return (1.0f - e) / (1.0f + e);
}

DEV void mfma16(f32x4& d, s16x8 a, s16x8 b) {
  asm("v_mfma_f32_16x16x32_bf16 %0, %1, %2, %0" : "+v"(d) : "v"(a), "v"(b));
}

// ---- weight prep: WT2[n][k2], k2<640: hi([Wk;Wr][k][n]); k2>=640: lo ----
__global__ __launch_bounds__(256)
void prep_w2(const float* __restrict__ Wk, const float* __restrict__ Wr,
             short* __restrict__ WT2) {
  __shared__ float t[64 * 65];
  const int k0 = blockIdx.x * 64, n0 = blockIdx.y * 64;
  const int c = threadIdx.x & 63, r4 = threadIdx.x >> 6;
#pragma unroll
  for (int i = 0; i < 16; ++i) {
    int r = r4 * 16 + i;
    int k = k0 + r, n = n0 + c;
    t[r * 65 + c] = (k < 128) ? Wk[(size_t)k * 2048 + n] : Wr[(size_t)(k - 128) * 2048 + n];
  }
  __syncthreads();
#pragma unroll
  for (int i = 0; i < 16; ++i) {
    int nn = r4 * 16 + i;
    float v = t[c * 65 + nn];
    short hi, lo; split2(v, hi, lo);
    WT2[(size_t)(n0 + nn) * 1280 + k0 + c] = hi;
    WT2[(size_t)(n0 + nn) * 1280 + 640 + k0 + c] = lo;
  }
}

// ---- WdT2[n][k2], k2<512: hi(Wd[k][n]); k2>=512: lo ----
__global__ __launch_bounds__(256)
void prep_wd2(const float* __restrict__ Wd, short* __restrict__ WdT2) {
  __shared__ float t[64 * 65];
  const int k0 = blockIdx.x * 64, n0 = blockIdx.y * 64;
  const int c = threadIdx.x & 63, r4 = threadIdx.x >> 6;
#pragma unroll
  for (int i = 0; i < 16; ++i) {
    int r = r4 * 16 + i;
    t[r * 65 + c] = Wd[(size_t)(k0 + r) * 128 + (n0 + c)];
  }
  __syncthreads();
#pragma unroll
  for (int i = 0; i < 16; ++i) {
    int nn = r4 * 16 + i;
    float v = t[c * 65 + nn];
    short hi, lo; split2(v, hi, lo);
    WdT2[(size_t)(n0 + nn) * 1024 + k0 + c] = hi;
    WdT2[(size_t)(n0 + nn) * 1024 + 512 + k0 + c] = lo;
  }
}

// ---------------- fused LSTM step (split-K precision) ----------------
// K' = 1280: [x_hi(128) | h_hi(512) | x_lo(128) | h_lo(512)]
// block: 64 m x 32 u, all 4 gates. grid 256 (XCD-local u-strips).
template <int XMODE>  // 0: x from f32 inputs; 1: x from split Phi/Plo
__global__ __launch_bounds__(256)
void lstm_step(const float* __restrict__ xf32,
               const short* __restrict__ Xhi, const short* __restrict__ Xlo,
               const short* __restrict__ Hhi, const short* __restrict__ Hlo,
               short* __restrict__ HhiO, short* __restrict__ HloO,
               float* __restrict__ Cst,
               const short* __restrict__ WT2,
               const float* __restrict__ bias) {
  __shared__ char lds[49152];
  char* const Ab[2] = { lds, lds + 24576 };
  char* const Bb[2] = { lds + 8192, lds + 32768 };
  const int tid = threadIdx.x;
  const int lane = tid & 63;
  const int wid = tid >> 6;
  const int wm = wid & 1, wu = wid >> 1;
  const int bid = blockIdx.x;
  const int jb = bid >> 3;
  const int strip = (bid & 7) + ((jb >> 4) << 3);  // strips XCD-local
  const int m0 = (jb & 15) * 64;
  const int u0 = strip * 32;
  const int wbase = (tid & 192) * 16;

  auto stageB = [&](int kt, char* B) {
#pragma unroll
    for (int p = 0; p < 4; ++p) {
      int idx = p * 256 + tid;
      int r = idx >> 3, jp = idx & 7;
      int j = jp ^ (r & 7);
      int gu = ((r >> 5) << 9) + u0 + (r & 31);
      gld_lds16(WT2 + (size_t)gu * 1280 + kt * 64 + j * 8, B + p * 4096 + wbase);
    }
  };
  auto stageA_g = [&](const short* base, int koff, int stride, char* A) {
#pragma unroll
    for (int p = 0; p < 2; ++p) {
      int idx = p * 256 + tid;
      int r = idx >> 3, jp = idx & 7;
      int j = jp ^ (r & 7);
      gld_lds16(base + (size_t)(m0 + r) * stride + koff + j * 8, A + p * 4096 + wbase);
    }
  };
  auto stageA_c = [&](int koff, int lopass, char* A) {  // f32 x -> bf16 hi or lo
#pragma unroll
    for (int p = 0; p < 2; ++p) {
      int idx = p * 256 + tid;
      int r = idx >> 3, jp = idx & 7;
      int j = jp ^ (r & 7);
      const float* s = xf32 + (size_t)(m0 + r) * 16384 + koff + j * 8;
      floatx4 a = *(const floatx4*)s;
      floatx4 b = *(const floatx4*)(s + 4);
      s16x8 v;
#pragma unroll
      for (int e = 0; e < 8; ++e) {
        float x = (e < 4) ? a[e] : b[e - 4];
        short hi = f2bf(x);
        v[e] = lopass ? f2bf(x - bf2f(hi)) : hi;
      }
      *(s16x8*)(A + idx * 16) = v;
    }
  };
  auto stage = [&](int kt, int bsel) {
    stageB(kt, Bb[bsel]);
    char* A = Ab[bsel];
    if (kt < 2) {
      if (XMODE == 0) stageA_c(kt * 64, 0, A);
      else stageA_g(Xhi, kt * 64, 128, A);
    } else if (kt < 10) {
      stageA_g(Hhi, (kt - 2) * 64, 512, A);
    } else if (kt < 12) {
      if (XMODE == 0) stageA_c((kt - 10) * 64, 1, A);
      else stageA_g(Xlo, (kt - 10) * 64, 128, A);
    } else {
      stageA_g(Hlo, (kt - 12) * 64, 512, A);
    }
  };

  f32x4 acc[2][4] = {};
  stage(0, 0);
  __syncthreads();
#pragma unroll
  for (int kt = 0; kt < 20; ++kt) {
    if (kt < 19) stage(kt + 1, (kt + 1) & 1);
    const char* A = Ab[kt & 1];
    const char* B = Bb[kt & 1];
#pragma unroll
    for (int s = 0; s < 2; ++s) {
      const int jd = s * 4 + (lane >> 4);
      s16x8 av[2], bv[4];
#pragma unroll
      for (int mi = 0; mi < 2; ++mi) {
        int r = wm * 32 + mi * 16 + (lane & 15);
        av[mi] = *(const s16x8*)(A + r * 128 + ((jd ^ (r & 7)) << 4));
      }
#pragma unroll
      for (int g = 0; g < 4; ++g) {
        int rB = g * 32 + wu * 16 + (lane & 15);
        bv[g] = *(const s16x8*)(B + rB * 128 + ((jd ^ (rB & 7)) << 4));
      }
#pragma unroll
      for (int mi = 0; mi < 2; ++mi)
#pragma unroll
        for (int g = 0; g < 4; ++g) mfma16(acc[mi][g], av[mi], bv[g]);
    }
    __syncthreads();
  }

  asm volatile("s_nop 7\ns_nop 7\ns_nop 7");

  const int u = u0 + wu * 16 + (lane & 15);
  const float bi = bias[u], bf_ = bias[512 + u], bg = bias[1024 + u], bo = bias[1536 + u];
#pragma unroll
  for (int mi = 0; mi < 2; ++mi) {
#pragma unroll
    for (int rr = 0; rr < 4; ++rr) {
      const int m = m0 + wm * 32 + mi * 16 + ((lane >> 4) << 2) + rr;
      const size_t off = (size_t)m * 512 + u;
      float ig = sigf(acc[mi][0][rr] + bi);
      float fg = sigf(acc[mi][1][rr] + bf_);
      float gg = tanhf2(acc[mi][2][rr] + bg);
      float og = sigf(acc[mi][3][rr] + bo);
      float cn = fg * Cst[off] + ig * gg;
      Cst[off] = cn;
      float hv = og * tanhf2(cn);
      short hh, hl; split2(hv, hh, hl);
      HhiO[off] = hh;
      HloO[off] = hl;
    }
  }
}

// ---------------- projection: p = h @ Wd + bd (split-K 1024) ----------------
__global__ __launch_bounds__(256)
void proj_kernel(const short* __restrict__ Hhi, const short* __restrict__ Hlo,
                 const short* __restrict__ WdT2,
                 const float* __restrict__ bd, float* __restrict__ out,
                 short* __restrict__ Phi, short* __restrict__ Plo,
                 int sstep, int S) {
  __shared__ char lds[40960];
  char* const Ab[2] = { lds, lds + 20480 };
  char* const Bb[2] = { lds + 4096, lds + 24576 };
  const int tid = threadIdx.x;
  const int lane = tid & 63;
  const int wid = tid >> 6;
  const int m0 = blockIdx.x * 32;
  const int wbase = (tid & 192) * 16;

  auto stage = [&](int kt, int bsel) {
    const short* Abase = (kt < 8) ? Hhi : Hlo;
    const int koff = (kt < 8) ? kt * 64 : (kt - 8) * 64;
    {
      int r = tid >> 3, jp = tid & 7;
      int j = jp ^ (r & 7);
      gld_lds16(Abase + (size_t)(m0 + r) * 512 + koff + j * 8, Ab[bsel] + wbase);
    }
#pragma unroll
    for (int p = 0; p < 4; ++p) {
      int idx = p * 256 + tid;
      int r = idx >> 3, jp = idx & 7;
      int j = jp ^ (r & 7);
      gld_lds16(WdT2 + (size_t)r * 1024 + kt * 64 + j * 8, Bb[bsel] + p * 4096 + wbase);
    }
  };

  f32x4 acc[2][2] = {};
  stage(0, 0);
  __syncthreads();
#pragma unroll
  for (int kt = 0; kt < 16; ++kt) {
    if (kt < 15) stage(kt + 1, (kt + 1) & 1);
    const char* A = Ab[kt & 1];
    const char* B = Bb[kt & 1];
#pragma unroll
    for (int s = 0; s < 2; ++s) {
      const int jd = s * 4 + (lane >> 4);
      s16x8 av[2], bv[2];
#pragma unroll
      for (int mi = 0; mi < 2; ++mi) {
        int r = mi * 16 + (lane & 15);
        av[mi] = *(const s16x8*)(A + r * 128 + ((jd ^ (r & 7)) << 4));
      }
#pragma unroll
      for (int nj = 0; nj < 2; ++nj) {
        int rB = wid * 32 + nj * 16 + (lane & 15);
        bv[nj] = *(const s16x8*)(B + rB * 128 + ((jd ^ (rB & 7)) << 4));
      }
#pragma unroll
      for (int mi = 0; mi < 2; ++mi)
#pragma unroll
        for (int nj = 0; nj < 2; ++nj) mfma16(acc[mi][nj], av[mi], bv[nj]);
    }
    __syncthreads();
  }

  asm volatile("s_nop 7\ns_nop 7\ns_nop 7");

#pragma unroll
  for (int nj = 0; nj < 2; ++nj) {
    const int n = wid * 32 + nj * 16 + (lane & 15);
    const float bb = bd[n];
#pragma unroll
    for (int mi = 0; mi < 2; ++mi) {
#pragma unroll
      for (int rr = 0; rr < 4; ++rr) {
        const int m = m0 + mi * 16 + ((lane >> 4) << 2) + rr;
        const float v = acc[mi][nj][rr] + bb;
        out[(size_t)m * ((size_t)S * 128) + (size_t)sstep * 128 + n] = v;
        short hi, lo; split2(v, hi, lo);
        Phi[m * 128 + n] = hi;
        Plo[m * 128 + n] = lo;
      }
    }
  }
}

extern "C" void kernel_launch(void* const* d_in, const int* in_sizes, int n_in,
                              void* d_out, int out_size, void* d_ws, size_t ws_size,
                              hipStream_t stream) {
  const float* inputs = (const float*)d_in[0];  // [1024,128,128]
  const float* Wk = (const float*)d_in[1];      // [128,2048]
  const float* Wr = (const float*)d_in[2];      // [512,2048]
  const float* bias = (const float*)d_in[3];    // [2048]
  const float* Wd = (const float*)d_in[4];      // [512,128]
  const float* bd = (const float*)d_in[5];      // [128]
  float* out = (float*)d_out;                   // [1024, S, 128]
  const int S = out_size / (1024 * 128);

  char* w = (char*)d_ws;
  short* WT2  = (short*)w; w += (size_t)2048 * 1280 * 2;  // 5.24 MB
  short* WdT2 = (short*)w; w += (size_t)128 * 1024 * 2;   // 0.26 MB
  short* Hhi0 = (short*)w; w += (size_t)1024 * 512 * 2;
  short* Hlo0 = (short*)w; w += (size_t)1024 * 512 * 2;
  short* Hhi1 = (short*)w; w += (size_t)1024 * 512 * 2;
  short* Hlo1 = (short*)w; w += (size_t)1024 * 512 * 2;
  float* Cst  = (float*)w; w += (size_t)1024 * 512 * 4;
  short* Phi  = (short*)w; w += (size_t)1024 * 128 * 2;
  short* Plo  = (short*)w; w += (size_t)1024 * 128 * 2;

  hipMemsetAsync(Hhi0, 0, (size_t)1024 * 512 * 2, stream);
  hipMemsetAsync(Hlo0, 0, (size_t)1024 * 512 * 2, stream);
  hipMemsetAsync(Cst, 0, (size_t)1024 * 512 * 4, stream);

  prep_w2<<<dim3(10, 32), 256, 0, stream>>>(Wk, Wr, WT2);
  prep_wd2<<<dim3(8, 2), 256, 0, stream>>>(Wd, WdT2);

  short* Hh[2] = { Hhi0, Hhi1 };
  short* Hl[2] = { Hlo0, Hlo1 };
  int p = 0;
  for (int t = 0; t < 128; ++t) {
    lstm_step<0><<<256, 256, 0, stream>>>(
        inputs + (size_t)t * 128, nullptr, nullptr,
        Hh[p], Hl[p], Hh[p ^ 1], Hl[p ^ 1], Cst, WT2, bias);
    p ^= 1;
  }
  proj_kernel<<<32, 256, 0, stream>>>(Hh[p], Hl[p], WdT2, bd, out, Phi, Plo, 0, S);
  for (int s = 1; s < S; ++s) {
    lstm_step<1><<<256, 256, 0, stream>>>(
        nullptr, Phi, Plo,
        Hh[p], Hl[p], Hh[p ^ 1], Hl[p ^ 1], Cst, WT2, bias);
    p ^= 1;
    proj_kernel<<<32, 256, 0, stream>>>(Hh[p], Hl[p], WdT2, bd, out, Phi, Plo, s, S);
  }
}

// Round 4
// 3297.147 us; speedup vs baseline: 1.3107x; 1.3107x over previous
//
#include <hip/hip_runtime.h>
#include <hip/hip_bf16.h>

typedef float f32x4 __attribute__((ext_vector_type(4)));
typedef short s16x8 __attribute__((ext_vector_type(8)));
typedef float floatx4 __attribute__((ext_vector_type(4)));

#define DEV static __device__ __forceinline__

DEV void gld_lds16(const void* g, void* l) {
  __builtin_amdgcn_global_load_lds(
      (const __attribute__((address_space(1))) void*)g,
      (__attribute__((address_space(3))) void*)l, 16, 0, 0);
}

DEV short f2bf(float x) {
  union { __hip_bfloat16 h; short s; } u;
  u.h = __float2bfloat16(x);
  return u.s;
}

DEV float bf2f(short s) {
  union { unsigned u; float f; } v;
  v.u = ((unsigned)(unsigned short)s) << 16;
  return v.f;
}

DEV void split2(float x, short& hi, short& lo) {
  hi = f2bf(x);
  lo = f2bf(x - bf2f(hi));
}

DEV float sigf(float x) {
  return 1.0f / (1.0f + exp2f(x * -1.44269504f));
}

DEV float tanhf2(float x) {
  float e = exp2f(fmaxf(x, -18.0f) * -2.88539008f);
  return (1.0f - e) / (1.0f + e);
}

DEV void mfma16(f32x4& d, s16x8 a, s16x8 b) {
  asm("v_mfma_f32_16x16x32_bf16 %0, %1, %2, %0" : "+v"(d) : "v"(a), "v"(b));
}

// ---- warmup weights: WT2[n][k2], k2<640: hi([Wk;Wr][k][n]); k2>=640: lo ----
__global__ __launch_bounds__(256)
void prep_w2(const float* __restrict__ Wk, const float* __restrict__ Wr,
             short* __restrict__ WT2) {
  __shared__ float t[64 * 65];
  const int k0 = blockIdx.x * 64, n0 = blockIdx.y * 64;
  const int c = threadIdx.x & 63, r4 = threadIdx.x >> 6;
#pragma unroll
  for (int i = 0; i < 16; ++i) {
    int r = r4 * 16 + i;
    int k = k0 + r, n = n0 + c;
    t[r * 65 + c] = (k < 128) ? Wk[(size_t)k * 2048 + n] : Wr[(size_t)(k - 128) * 2048 + n];
  }
  __syncthreads();
#pragma unroll
  for (int i = 0; i < 16; ++i) {
    int nn = r4 * 16 + i;
    float v = t[c * 65 + nn];
    short hi, lo; split2(v, hi, lo);
    WT2[(size_t)(n0 + nn) * 1280 + k0 + c] = hi;
    WT2[(size_t)(n0 + nn) * 1280 + 640 + k0 + c] = lo;
  }
}

// ---- WdecAll rows 0..2047: Wdec[k'][n] = Wr + Wd@Wk, computed f32, split, transposed ----
__global__ __launch_bounds__(256)
void wdec_split(const float* __restrict__ Wd, const float* __restrict__ Wk,
                const float* __restrict__ Wr, short* __restrict__ WdecAll) {
  const int n = blockIdx.x * 256 + threadIdx.x;  // 0..2047
  const int kp = blockIdx.y;                     // 0..511
  float acc = Wr[(size_t)kp * 2048 + n];
#pragma unroll 8
  for (int j = 0; j < 128; ++j)
    acc = fmaf(Wd[(size_t)kp * 128 + j], Wk[(size_t)j * 2048 + n], acc);
  short hi, lo; split2(acc, hi, lo);
  WdecAll[(size_t)n * 1024 + kp] = hi;
  WdecAll[(size_t)n * 1024 + 512 + kp] = lo;
}

// ---- WdecAll rows 2048..2175: Wd columns (for fused/final projection) ----
__global__ __launch_bounds__(256)
void wd_append(const float* __restrict__ Wd, short* __restrict__ WdecAll) {
  const int t = blockIdx.x * 256 + threadIdx.x;  // 0..65535
  const int k = t >> 7, n = t & 127;
  float v = Wd[(size_t)k * 128 + n];
  short hi, lo; split2(v, hi, lo);
  WdecAll[(size_t)(2048 + n) * 1024 + k] = hi;
  WdecAll[(size_t)(2048 + n) * 1024 + 512 + k] = lo;
}

// ---- bdecAll[0..2047] = b + bd@Wk ; [2048..2175] = bd ----
__global__ __launch_bounds__(256)
void bdec_all(const float* __restrict__ bd, const float* __restrict__ Wk,
              const float* __restrict__ b, float* __restrict__ bdecAll) {
  const int n = blockIdx.x * 256 + threadIdx.x;
  if (n < 2048) {
    float acc = b[n];
#pragma unroll 8
    for (int j = 0; j < 128; ++j) acc = fmaf(bd[j], Wk[(size_t)j * 2048 + n], acc);
    bdecAll[n] = acc;
  } else if (n < 2176) {
    bdecAll[n] = bd[n - 2048];
  }
}

// ---------------- fused LSTM step (split-K precision) ----------------
// XMODE 0 (warmup): grid 256. K'=1280: [x_hi|h_hi|x_lo|h_lo], W=WT2[2048][1280], bias=b.
// XMODE 2 (decode): grid 272. K'=1024: [h_hi|h_lo], W=WdecAll[2176][1024], bias=bdecAll.
//   blocks 0..255: gate strips (update h,c). blocks 256..271: proj strip -> out[:,sidx,:].
// XMODE 3 (final proj): grid 16. proj strip only -> out[:,sidx,:].
template <int XMODE>
__global__ __launch_bounds__(256)
void lstm_step(const float* __restrict__ xf32,
               const short* __restrict__ Hhi, const short* __restrict__ Hlo,
               short* __restrict__ HhiO, short* __restrict__ HloO,
               float* __restrict__ Cst,
               const short* __restrict__ W2,
               const float* __restrict__ bias,
               float* __restrict__ out, int sidx, int S) {
  constexpr int NKT = (XMODE == 0) ? 20 : 16;
  constexpr int KP = (XMODE == 0) ? 1280 : 1024;
  __shared__ char lds[49152];
  char* const Ab[2] = { lds, lds + 24576 };
  char* const Bb[2] = { lds + 8192, lds + 32768 };
  const int tid = threadIdx.x;
  const int lane = tid & 63;
  const int wid = tid >> 6;
  const int wm = wid & 1, wu = wid >> 1;
  const int bid = blockIdx.x;

  bool is16;
  int m0, u0;
  if (XMODE == 3) {
    is16 = true; m0 = bid * 64; u0 = 0;
  } else if (XMODE == 2 && bid >= 256) {
    is16 = true; m0 = (bid - 256) * 64; u0 = 0;
  } else {
    is16 = false;
    const int jb = bid >> 3;
    const int strip = (bid & 7) + ((jb >> 4) << 3);  // strips XCD-local
    m0 = (jb & 15) * 64;
    u0 = strip * 32;
  }
  const int wbase = (tid & 192) * 16;

  auto stageB = [&](int kt, char* B) {
#pragma unroll
    for (int p = 0; p < 4; ++p) {
      int idx = p * 256 + tid;
      int r = idx >> 3, jp = idx & 7;
      int j = jp ^ (r & 7);
      int gu = is16 ? (2048 + r) : (((r >> 5) << 9) + u0 + (r & 31));
      gld_lds16(W2 + (size_t)gu * KP + kt * 64 + j * 8, B + p * 4096 + wbase);
    }
  };
  auto stageA_g = [&](const short* base, int koff, char* A) {
#pragma unroll
    for (int p = 0; p < 2; ++p) {
      int idx = p * 256 + tid;
      int r = idx >> 3, jp = idx & 7;
      int j = jp ^ (r & 7);
      gld_lds16(base + (size_t)(m0 + r) * 512 + koff + j * 8, A + p * 4096 + wbase);
    }
  };
  auto stageA_c = [&](int koff, int lopass, char* A) {  // f32 x -> bf16 hi or lo
#pragma unroll
    for (int p = 0; p < 2; ++p) {
      int idx = p * 256 + tid;
      int r = idx >> 3, jp = idx & 7;
      int j = jp ^ (r & 7);
      const float* s = xf32 + (size_t)(m0 + r) * 16384 + koff + j * 8;
      floatx4 a = *(const floatx4*)s;
      floatx4 b = *(const floatx4*)(s + 4);
      s16x8 v;
#pragma unroll
      for (int e = 0; e < 8; ++e) {
        float x = (e < 4) ? a[e] : b[e - 4];
        short hi = f2bf(x);
        v[e] = lopass ? f2bf(x - bf2f(hi)) : hi;
      }
      *(s16x8*)(A + idx * 16) = v;
    }
  };
  auto stage = [&](int kt, int bsel) {
    stageB(kt, Bb[bsel]);
    char* A = Ab[bsel];
    if (XMODE == 0) {
      if (kt < 2) stageA_c(kt * 64, 0, A);
      else if (kt < 10) stageA_g(Hhi, (kt - 2) * 64, A);
      else if (kt < 12) stageA_c((kt - 10) * 64, 1, A);
      else stageA_g(Hlo, (kt - 12) * 64, A);
    } else {
      if (kt < 8) stageA_g(Hhi, kt * 64, A);
      else stageA_g(Hlo, (kt - 8) * 64, A);
    }
  };

  f32x4 acc[2][4] = {};
  stage(0, 0);
  __syncthreads();
#pragma unroll
  for (int kt = 0; kt < NKT; ++kt) {
    if (kt < NKT - 1) stage(kt + 1, (kt + 1) & 1);
    const char* A = Ab[kt & 1];
    const char* B = Bb[kt & 1];
#pragma unroll
    for (int s = 0; s < 2; ++s) {
      const int jd = s * 4 + (lane >> 4);
      s16x8 av[2], bv[4];
#pragma unroll
      for (int mi = 0; mi < 2; ++mi) {
        int r = wm * 32 + mi * 16 + (lane & 15);
        av[mi] = *(const s16x8*)(A + r * 128 + ((jd ^ (r & 7)) << 4));
      }
#pragma unroll
      for (int g = 0; g < 4; ++g) {
        int rB = g * 32 + wu * 16 + (lane & 15);
        bv[g] = *(const s16x8*)(B + rB * 128 + ((jd ^ (rB & 7)) << 4));
      }
#pragma unroll
      for (int mi = 0; mi < 2; ++mi)
#pragma unroll
        for (int g = 0; g < 4; ++g) mfma16(acc[mi][g], av[mi], bv[g]);
    }
    __syncthreads();
  }

  asm volatile("s_nop 7\ns_nop 7\ns_nop 7");

  if (XMODE == 3 || (XMODE == 2 && is16)) {
    // projection epilogue: n = g*32 + wu*16 + (lane&15), p = acc + bd[n]
#pragma unroll
    for (int g = 0; g < 4; ++g) {
      const int n = g * 32 + wu * 16 + (lane & 15);
      const float bb = bias[2048 + n];
#pragma unroll
      for (int mi = 0; mi < 2; ++mi) {
#pragma unroll
        for (int rr = 0; rr < 4; ++rr) {
          const int m = m0 + wm * 32 + mi * 16 + ((lane >> 4) << 2) + rr;
          out[(size_t)m * ((size_t)S * 128) + (size_t)sidx * 128 + n] =
              acc[mi][g][rr] + bb;
        }
      }
    }
    return;
  }

  const int u = u0 + wu * 16 + (lane & 15);
  const float bi = bias[u], bf_ = bias[512 + u], bg = bias[1024 + u], bo = bias[1536 + u];
#pragma unroll
  for (int mi = 0; mi < 2; ++mi) {
#pragma unroll
    for (int rr = 0; rr < 4; ++rr) {
      const int m = m0 + wm * 32 + mi * 16 + ((lane >> 4) << 2) + rr;
      const size_t off = (size_t)m * 512 + u;
      float ig = sigf(acc[mi][0][rr] + bi);
      float fg = sigf(acc[mi][1][rr] + bf_);
      float gg = tanhf2(acc[mi][2][rr] + bg);
      float og = sigf(acc[mi][3][rr] + bo);
      float cn = fg * Cst[off] + ig * gg;
      Cst[off] = cn;
      float hv = og * tanhf2(cn);
      short hh, hl; split2(hv, hh, hl);
      HhiO[off] = hh;
      HloO[off] = hl;
    }
  }
}

extern "C" void kernel_launch(void* const* d_in, const int* in_sizes, int n_in,
                              void* d_out, int out_size, void* d_ws, size_t ws_size,
                              hipStream_t stream) {
  const float* inputs = (const float*)d_in[0];  // [1024,128,128]
  const float* Wk = (const float*)d_in[1];      // [128,2048]
  const float* Wr = (const float*)d_in[2];      // [512,2048]
  const float* bias = (const float*)d_in[3];    // [2048]
  const float* Wd = (const float*)d_in[4];      // [512,128]
  const float* bd = (const float*)d_in[5];      // [128]
  float* out = (float*)d_out;                   // [1024, S, 128]
  const int S = out_size / (1024 * 128);        // 96

  char* w = (char*)d_ws;
  short* WT2     = (short*)w; w += (size_t)2048 * 1280 * 2;  // 5.24 MB
  short* WdecAll = (short*)w; w += (size_t)2176 * 1024 * 2;  // 4.46 MB
  float* bdecA   = (float*)w; w += (size_t)2176 * 4;         // 8.7 KB
  short* Hhi0 = (short*)w; w += (size_t)1024 * 512 * 2;
  short* Hlo0 = (short*)w; w += (size_t)1024 * 512 * 2;
  short* Hhi1 = (short*)w; w += (size_t)1024 * 512 * 2;
  short* Hlo1 = (short*)w; w += (size_t)1024 * 512 * 2;      // 4x 1.05 MB
  float* Cst  = (float*)w; w += (size_t)1024 * 512 * 4;      // 2.10 MB
  if ((size_t)(w - (char*)d_ws) > ws_size) return;           // clean fail, no corruption

  hipMemsetAsync(Hhi0, 0, (size_t)1024 * 512 * 2, stream);
  hipMemsetAsync(Hlo0, 0, (size_t)1024 * 512 * 2, stream);
  hipMemsetAsync(Cst, 0, (size_t)1024 * 512 * 4, stream);

  // one-time weight prep
  prep_w2<<<dim3(10, 32), 256, 0, stream>>>(Wk, Wr, WT2);
  wdec_split<<<dim3(8, 512), 256, 0, stream>>>(Wd, Wk, Wr, WdecAll);
  wd_append<<<256, 256, 0, stream>>>(Wd, WdecAll);
  bdec_all<<<9, 256, 0, stream>>>(bd, Wk, bias, bdecA);

  // warmup: 128 steps
  short* Hh[2] = { Hhi0, Hhi1 };
  short* Hl[2] = { Hlo0, Hlo1 };
  int p = 0;
  for (int t = 0; t < 128; ++t) {
    lstm_step<0><<<256, 256, 0, stream>>>(
        inputs + (size_t)t * 128, Hh[p], Hl[p], Hh[p ^ 1], Hl[p ^ 1], Cst,
        WT2, bias, nullptr, 0, S);
    p ^= 1;
  }

  // decode: 95 fused steps (gate blocks update h,c; proj blocks emit out[:,s-1,:])
  for (int s = 1; s < S; ++s) {
    lstm_step<2><<<272, 256, 0, stream>>>(
        nullptr, Hh[p], Hl[p], Hh[p ^ 1], Hl[p ^ 1], Cst,
        WdecAll, bdecA, out, s - 1, S);
    p ^= 1;
  }
  // final projection for step S-1
  lstm_step<3><<<16, 256, 0, stream>>>(
      nullptr, Hh[p], Hl[p], Hh[p], Hl[p], Cst,
      WdecAll, bdecA, out, S - 1, S);
}

// Round 5
// 2891.026 us; speedup vs baseline: 1.4948x; 1.1405x over previous
//
#include <hip/hip_runtime.h>
#include <hip/hip_bf16.h>

typedef float f32x4 __attribute__((ext_vector_type(4)));
typedef short s16x8 __attribute__((ext_vector_type(8)));
typedef float floatx4 __attribute__((ext_vector_type(4)));

#define DEV static __device__ __forceinline__
#define WAITVM(N) asm volatile("s_waitcnt vmcnt(" #N ")" ::: "memory")

DEV void barrier_pipe() {
  __builtin_amdgcn_sched_barrier(0);
  __builtin_amdgcn_s_barrier();
  __builtin_amdgcn_sched_barrier(0);
}

DEV void gld_lds16(const void* g, void* l) {
  __builtin_amdgcn_global_load_lds(
      (const __attribute__((address_space(1))) void*)g,
      (__attribute__((address_space(3))) void*)l, 16, 0, 0);
}

DEV short f2bf(float x) {
  union { __hip_bfloat16 h; short s; } u;
  u.h = __float2bfloat16(x);
  return u.s;
}

DEV float bf2f(short s) {
  union { unsigned u; float f; } v;
  v.u = ((unsigned)(unsigned short)s) << 16;
  return v.f;
}

DEV void split2(float x, short& hi, short& lo) {
  hi = f2bf(x);
  lo = f2bf(x - bf2f(hi));
}

DEV float sigf(float x) {
  return 1.0f / (1.0f + exp2f(x * -1.44269504f));
}

DEV float tanhf2(float x) {
  float e = exp2f(fmaxf(x, -18.0f) * -2.88539008f);
  return (1.0f - e) / (1.0f + e);
}

DEV void mfma16(f32x4& d, s16x8 a, s16x8 b) {
  asm("v_mfma_f32_16x16x32_bf16 %0, %1, %2, %0" : "+v"(d) : "v"(a), "v"(b));
}

// ---- warmup weights: WT2[n][k2]: [Wk_hi(128)|Wr_hi(512)|Wk_lo(128)|Wr_lo(512)] ----
__global__ __launch_bounds__(256)
void prep_w2(const float* __restrict__ Wk, const float* __restrict__ Wr,
             short* __restrict__ WT2) {
  __shared__ float t[64 * 65];
  const int k0 = blockIdx.x * 64, n0 = blockIdx.y * 64;
  const int c = threadIdx.x & 63, r4 = threadIdx.x >> 6;
#pragma unroll
  for (int i = 0; i < 16; ++i) {
    int r = r4 * 16 + i;
    int k = k0 + r, n = n0 + c;
    t[r * 65 + c] = (k < 128) ? Wk[(size_t)k * 2048 + n] : Wr[(size_t)(k - 128) * 2048 + n];
  }
  __syncthreads();
#pragma unroll
  for (int i = 0; i < 16; ++i) {
    int nn = r4 * 16 + i;
    float v = t[c * 65 + nn];
    short hi, lo; split2(v, hi, lo);
    WT2[(size_t)(n0 + nn) * 1280 + k0 + c] = hi;
    WT2[(size_t)(n0 + nn) * 1280 + 640 + k0 + c] = lo;
  }
}

// ---- WdecAll rows 0..2047: Wdec = Wr + Wd@Wk (f32), split hi|lo over K=512 ----
__global__ __launch_bounds__(256)
void wdec_split(const float* __restrict__ Wd, const float* __restrict__ Wk,
                const float* __restrict__ Wr, short* __restrict__ WdecAll) {
  const int n = blockIdx.x * 256 + threadIdx.x;  // 0..2047
  const int kp = blockIdx.y;                     // 0..511
  float acc = Wr[(size_t)kp * 2048 + n];
#pragma unroll 8
  for (int j = 0; j < 128; ++j)
    acc = fmaf(Wd[(size_t)kp * 128 + j], Wk[(size_t)j * 2048 + n], acc);
  short hi, lo; split2(acc, hi, lo);
  WdecAll[(size_t)n * 1024 + kp] = hi;
  WdecAll[(size_t)n * 1024 + 512 + kp] = lo;
}

// ---- WdecAll rows 2048..2175: Wd columns ----
__global__ __launch_bounds__(256)
void wd_append(const float* __restrict__ Wd, short* __restrict__ WdecAll) {
  const int t = blockIdx.x * 256 + threadIdx.x;  // 0..65535
  const int k = t >> 7, n = t & 127;
  float v = Wd[(size_t)k * 128 + n];
  short hi, lo; split2(v, hi, lo);
  WdecAll[(size_t)(2048 + n) * 1024 + k] = hi;
  WdecAll[(size_t)(2048 + n) * 1024 + 512 + k] = lo;
}

// ---- bdecAll[0..2047] = b + bd@Wk ; [2048..2175] = bd ----
__global__ __launch_bounds__(256)
void bdec_all(const float* __restrict__ bd, const float* __restrict__ Wk,
              const float* __restrict__ b, float* __restrict__ bdecAll) {
  const int n = blockIdx.x * 256 + threadIdx.x;
  if (n < 2048) {
    float acc = b[n];
#pragma unroll 8
    for (int j = 0; j < 128; ++j) acc = fmaf(bd[j], Wk[(size_t)j * 2048 + n], acc);
    bdecAll[n] = acc;
  } else if (n < 2176) {
    bdecAll[n] = bd[n - 2048];
  }
}

// ---- x0 init: inputs[:,0,:] -> AW0 cols [0..127]=hi, [640..767]=lo ----
__global__ __launch_bounds__(256)
void x0_init(const float* __restrict__ inputs, short* __restrict__ AW0) {
  const int t = blockIdx.x * 256 + threadIdx.x;  // 16384
  const int r = t >> 4, c0 = (t & 15) * 8;
  const float* src = inputs + (size_t)r * 16384 + c0;
  floatx4 a = *(const floatx4*)src;
  floatx4 b = *(const floatx4*)(src + 4);
  s16x8 vh, vl;
#pragma unroll
  for (int e = 0; e < 8; ++e) {
    float x = (e < 4) ? a[e] : b[e - 4];
    short hi, lo; split2(x, hi, lo);
    vh[e] = hi; vl[e] = lo;
  }
  *(s16x8*)(AW0 + (size_t)r * 1280 + c0) = vh;
  *(s16x8*)(AW0 + (size_t)r * 1280 + 640 + c0) = vl;
}

// ---------------- pipelined LSTM step ----------------
// MODE 0 (warmup): grid 256 gate blocks. A=[x_hi|h_hi|x_lo|h_lo] (stride 1280), W=WT2, NKT=20.
// MODE 1 (decode): grid 272. blocks<256: gates; >=256: proj of h_{s-1} -> out[:,sidx,:].
//                  A=[h_hi|h_lo] (stride 1024), W=WdecAll(2176 rows), NKT=16.
// MODE 2 (proj-only): grid 16, all proj.
// 3-deep LDS ring, counted vmcnt (6 loads/thread/stage), raw s_barrier (1/kt).
template <int MODE>
__global__ __launch_bounds__(256)
void lstm_step(const short* __restrict__ Abuf,
               short* __restrict__ hout, int hstride, int hioff, int looff,
               const float* __restrict__ xnext,
               float* __restrict__ Cst,
               const short* __restrict__ W2,
               const float* __restrict__ bias,
               float* __restrict__ out, int sidx, int S) {
  constexpr int NKT = (MODE == 0) ? 20 : 16;
  constexpr int KP  = (MODE == 0) ? 1280 : 1024;   // also the A-row stride
  __shared__ char lds[73728];  // A ring: 3x8KB @0 ; B ring: 3x16KB @24576
  const int tid = threadIdx.x;
  const int lane = tid & 63;
  const int wid = tid >> 6;
  const int wm = wid & 1, wu = wid >> 1;
  const int bid = blockIdx.x;

  bool is16;
  int m0, u0;
  if (MODE == 2) {
    is16 = true; m0 = bid * 64; u0 = 0;
  } else if (MODE == 1 && bid >= 256) {
    is16 = true; m0 = (bid - 256) * 64; u0 = 0;
  } else {
    is16 = false;
    const int jb = bid >> 3;
    const int strip = (bid & 7) + ((jb >> 4) << 3);  // XCD-local strips
    m0 = (jb & 15) * 64;
    u0 = strip * 32;
  }
  const int wbase = (tid & 192) * 16;

  auto stage = [&](int kt, int bsel) {
    char* B = lds + 24576 + bsel * 16384;
#pragma unroll
    for (int p = 0; p < 4; ++p) {
      int idx = p * 256 + tid;
      int r = idx >> 3, jp = idx & 7;
      int j = jp ^ (r & 7);
      int gu = is16 ? (2048 + r) : (((r >> 5) << 9) + u0 + (r & 31));
      gld_lds16(W2 + (size_t)gu * KP + kt * 64 + j * 8, B + p * 4096 + wbase);
    }
    char* A = lds + bsel * 8192;
#pragma unroll
    for (int p = 0; p < 2; ++p) {
      int idx = p * 256 + tid;
      int r = idx >> 3, jp = idx & 7;
      int j = jp ^ (r & 7);
      gld_lds16(Abuf + (size_t)(m0 + r) * KP + kt * 64 + j * 8, A + p * 4096 + wbase);
    }
  };

  f32x4 acc[2][4] = {};
  stage(0, 0);
  stage(1, 1);
#pragma unroll
  for (int kt = 0; kt < NKT; ++kt) {
    if (kt <= NKT - 2) WAITVM(6);
    else WAITVM(0);
    barrier_pipe();
    if (kt + 2 < NKT) stage(kt + 2, (kt + 2) % 3);
    const char* A = lds + (kt % 3) * 8192;
    const char* B = lds + 24576 + (kt % 3) * 16384;
#pragma unroll
    for (int s2 = 0; s2 < 2; ++s2) {
      const int jd = s2 * 4 + (lane >> 4);
      s16x8 av[2], bv[4];
#pragma unroll
      for (int mi = 0; mi < 2; ++mi) {
        int r = wm * 32 + mi * 16 + (lane & 15);
        av[mi] = *(const s16x8*)(A + r * 128 + ((jd ^ (r & 7)) << 4));
      }
#pragma unroll
      for (int g = 0; g < 4; ++g) {
        int rB = g * 32 + wu * 16 + (lane & 15);
        bv[g] = *(const s16x8*)(B + rB * 128 + ((jd ^ (rB & 7)) << 4));
      }
#pragma unroll
      for (int mi = 0; mi < 2; ++mi)
#pragma unroll
        for (int g = 0; g < 4; ++g) mfma16(acc[mi][g], av[mi], bv[g]);
    }
  }

  asm volatile("s_nop 7\ns_nop 7\ns_nop 7");

  if (MODE == 2 || (MODE == 1 && is16)) {
    // projection epilogue: n = g*32 + wu*16 + (lane&15)
#pragma unroll
    for (int g = 0; g < 4; ++g) {
      const int n = g * 32 + wu * 16 + (lane & 15);
      const float bb = bias[2048 + n];
#pragma unroll
      for (int mi = 0; mi < 2; ++mi) {
#pragma unroll
        for (int rr = 0; rr < 4; ++rr) {
          const int m = m0 + wm * 32 + mi * 16 + ((lane >> 4) << 2) + rr;
          out[(size_t)m * ((size_t)S * 128) + (size_t)sidx * 128 + n] =
              acc[mi][g][rr] + bb;
        }
      }
    }
    return;
  }

  // gate epilogue
  const int u = u0 + wu * 16 + (lane & 15);
  const float bi = bias[u], bf_ = bias[512 + u], bg = bias[1024 + u], bo = bias[1536 + u];
#pragma unroll
  for (int mi = 0; mi < 2; ++mi) {
#pragma unroll
    for (int rr = 0; rr < 4; ++rr) {
      const int m = m0 + wm * 32 + mi * 16 + ((lane >> 4) << 2) + rr;
      const size_t off = (size_t)m * 512 + u;
      float ig = sigf(acc[mi][0][rr] + bi);
      float fg = sigf(acc[mi][1][rr] + bf_);
      float gg = tanhf2(acc[mi][2][rr] + bg);
      float og = sigf(acc[mi][3][rr] + bo);
      float cn = fg * Cst[off] + ig * gg;
      Cst[off] = cn;
      float hv = og * tanhf2(cn);
      short hh, hl; split2(hv, hh, hl);
      hout[(size_t)m * hstride + hioff + u] = hh;
      hout[(size_t)m * hstride + looff + u] = hl;
    }
  }

  // next-x conversion (warmup only; one strip's blocks cover all m)
  if (MODE == 0 && xnext != nullptr && u0 == 0) {
    const int r = tid >> 2;
    const int c0 = (tid & 3) * 32;
    const float* src = xnext + (size_t)(m0 + r) * 16384 + c0;
    short* dst = hout + (size_t)(m0 + r) * hstride;
#pragma unroll
    for (int j = 0; j < 32; j += 8) {
      floatx4 a = *(const floatx4*)(src + j);
      floatx4 b = *(const floatx4*)(src + j + 4);
      s16x8 vh, vl;
#pragma unroll
      for (int e = 0; e < 8; ++e) {
        float x = (e < 4) ? a[e] : b[e - 4];
        short hi, lo; split2(x, hi, lo);
        vh[e] = hi; vl[e] = lo;
      }
      *(s16x8*)(dst + c0 + j) = vh;
      *(s16x8*)(dst + 640 + c0 + j) = vl;
    }
  }
}

extern "C" void kernel_launch(void* const* d_in, const int* in_sizes, int n_in,
                              void* d_out, int out_size, void* d_ws, size_t ws_size,
                              hipStream_t stream) {
  const float* inputs = (const float*)d_in[0];  // [1024,128,128]
  const float* Wk = (const float*)d_in[1];      // [128,2048]
  const float* Wr = (const float*)d_in[2];      // [512,2048]
  const float* bias = (const float*)d_in[3];    // [2048]
  const float* Wd = (const float*)d_in[4];      // [512,128]
  const float* bd = (const float*)d_in[5];      // [128]
  float* out = (float*)d_out;                   // [1024, S, 128]
  const int S = out_size / (1024 * 128);        // 96

  char* w = (char*)d_ws;
  short* WT2     = (short*)w; w += (size_t)2048 * 1280 * 2;  // 5.24 MB
  short* WdecAll = (short*)w; w += (size_t)2176 * 1024 * 2;  // 4.46 MB
  float* bdecA   = (float*)w; w += (size_t)2176 * 4;
  short* AW0 = (short*)w; w += (size_t)1024 * 1280 * 2;      // 2.62 MB
  short* AW1 = (short*)w; w += (size_t)1024 * 1280 * 2;      // 2.62 MB
  short* AD0 = (short*)w; w += (size_t)1024 * 1024 * 2;      // 2.10 MB
  short* AD1 = (short*)w; w += (size_t)1024 * 1024 * 2;      // 2.10 MB
  float* Cst = (float*)w; w += (size_t)1024 * 512 * 4;       // 2.10 MB
  if ((size_t)(w - (char*)d_ws) > ws_size) return;           // clean fail

  hipMemsetAsync(AW0, 0, (size_t)1024 * 1280 * 2, stream);
  hipMemsetAsync(Cst, 0, (size_t)1024 * 512 * 4, stream);

  prep_w2<<<dim3(10, 32), 256, 0, stream>>>(Wk, Wr, WT2);
  wdec_split<<<dim3(8, 512), 256, 0, stream>>>(Wd, Wk, Wr, WdecAll);
  wd_append<<<256, 256, 0, stream>>>(Wd, WdecAll);
  bdec_all<<<9, 256, 0, stream>>>(bd, Wk, bias, bdecA);
  x0_init<<<64, 256, 0, stream>>>(inputs, AW0);

  short* AW[2] = { AW0, AW1 };
  short* AD[2] = { AD0, AD1 };

  // warmup: steps 0..126 write AW[(t+1)&1]; step 127 writes AD[0]
  for (int t = 0; t < 127; ++t) {
    lstm_step<0><<<256, 256, 0, stream>>>(
        AW[t & 1], AW[(t + 1) & 1], 1280, 128, 768,
        inputs + (size_t)(t + 1) * 128, Cst, WT2, bias, nullptr, 0, S);
  }
  lstm_step<0><<<256, 256, 0, stream>>>(
      AW[1], AD[0], 1024, 0, 512, nullptr, Cst, WT2, bias, nullptr, 0, S);

  // decode: step s computes h_s (gates) and out[:,s-1,:] (proj of h_{s-1})
  for (int s = 1; s < S; ++s) {
    lstm_step<1><<<272, 256, 0, stream>>>(
        AD[(s - 1) & 1], AD[s & 1], 1024, 0, 512, nullptr, Cst,
        WdecAll, bdecA, out, s - 1, S);
  }
  // final projection of h_{S-1}
  lstm_step<2><<<16, 256, 0, stream>>>(
      AD[(S - 1) & 1], nullptr, 0, 0, 0, nullptr, Cst,
      WdecAll, bdecA, out, S - 1, S);
}